// Round 1
// 384.586 us; speedup vs baseline: 1.6336x; 1.6336x over previous
//
#include <hip/hip_runtime.h>
#include <math.h>

// Problem constants
#define NB   16
#define CC   256
#define NPTS 16384       // 16*32*32
#define KK   8192
#define Z_OUT 4194304    // NPTS*CC
// d_out: [0,Z_OUT) z_q_out (BCHW), [Z_OUT,Z_OUT+NPTS) idx as float, [Z_OUT+NPTS] loss
// d_out scratch reuse timeline:
//   before k_phase1 done: zb16 = bf16[16384][256] at slot 0, ebf = bf16[8192][256] at slot 2,097,152
//   after  k_phase1:      z_t  = f32 [16384][256] over the whole [0, Z_OUT) region (k_tr_z)
//   k_gather finally overwrites [0, Z_OUT) with z_q BCHW.

// ws layout (floats)
#define WS_ZNORM 64
#define WS_ENORM 16448
#define WS_CCNT  24640                // int[16384] candidate counts
#define WS_CIDX  41024                // int[16384][64] candidate k lists
#define CAND_CAP 64
#define MARGIN   4.0e-4f              // > 2*eps_bf16 + d-quantum + enorm spread

typedef short v8s __attribute__((ext_vector_type(8)));
typedef float v4f __attribute__((ext_vector_type(4)));

__device__ __forceinline__ void gl_lds16(const void* g, void* l) {
    __builtin_amdgcn_global_load_lds((const __attribute__((address_space(1))) void*)g,
                                     (__attribute__((address_space(3))) void*)l, 16, 0, 0);
}
__device__ __forceinline__ unsigned short f2bf(float f) {   // RNE, finite inputs
    unsigned int u = __float_as_uint(f);
    return (unsigned short)((u + 0x7FFFu + ((u >> 16) & 1u)) >> 16);
}

// ---------------- P0: z BCHW fp32 -> zb16[n][c] bf16 (transpose+cast) ----------------
__global__ void k_prep_z(const float* __restrict__ z, unsigned short* __restrict__ zb16) {
    __shared__ float ts[64][65];
    const int hw0 = blockIdx.x * 64, c0 = blockIdx.y * 64, b = blockIdx.z;
    const int tid = threadIdx.x;
#pragma unroll
    for (int p = 0; p < 4; ++p) {
        int u = p * 256 + tid;
        int ci = u >> 4, j4 = (u & 15) << 2;
        float4 v = *(const float4*)(z + (size_t)b * 262144 + (size_t)(c0 + ci) * 1024 + hw0 + j4);
        ts[ci][j4 + 0] = v.x; ts[ci][j4 + 1] = v.y; ts[ci][j4 + 2] = v.z; ts[ci][j4 + 3] = v.w;
    }
    __syncthreads();
#pragma unroll
    for (int p = 0; p < 4; ++p) {
        int u = p * 256 + tid;
        int hj = u >> 4, i4 = (u & 15) << 2;
        ushort4 o = make_ushort4(f2bf(ts[i4 + 0][hj]), f2bf(ts[i4 + 1][hj]),
                                 f2bf(ts[i4 + 2][hj]), f2bf(ts[i4 + 3][hj]));
        *(ushort4*)(zb16 + (size_t)(b * 1024 + hw0 + hj) * 256 + c0 + i4) = o;
    }
}

// ---------------- P0b: z BCHW fp32 -> z_t[n][c] fp32 (transpose, runs after phase1) --
__global__ void k_tr_z(const float* __restrict__ z, float* __restrict__ zt) {
    __shared__ float ts[64][65];
    const int hw0 = blockIdx.x * 64, c0 = blockIdx.y * 64, b = blockIdx.z;
    const int tid = threadIdx.x;
#pragma unroll
    for (int p = 0; p < 4; ++p) {
        int u = p * 256 + tid;
        int ci = u >> 4, j4 = (u & 15) << 2;
        float4 v = *(const float4*)(z + (size_t)b * 262144 + (size_t)(c0 + ci) * 1024 + hw0 + j4);
        ts[ci][j4 + 0] = v.x; ts[ci][j4 + 1] = v.y; ts[ci][j4 + 2] = v.z; ts[ci][j4 + 3] = v.w;
    }
    __syncthreads();
#pragma unroll
    for (int p = 0; p < 4; ++p) {
        int u = p * 256 + tid;
        int hj = u >> 4, i4 = (u & 15) << 2;
        float4 o = make_float4(ts[i4 + 0][hj], ts[i4 + 1][hj], ts[i4 + 2][hj], ts[i4 + 3][hj]);
        *(float4*)(zt + (size_t)(b * 1024 + hw0 + hj) * 256 + c0 + i4) = o;
    }
}

// ---------------- P1: emb fp32 -> ebf[k][c] bf16 ----------------
__global__ void k_prep_e(const float* __restrict__ emb, unsigned short* __restrict__ ebf) {
    const int i = (blockIdx.x * 256 + threadIdx.x) * 8;
    float4 a = *(const float4*)(emb + i);
    float4 b = *(const float4*)(emb + i + 4);
    *(ushort4*)(ebf + i)     = make_ushort4(f2bf(a.x), f2bf(a.y), f2bf(a.z), f2bf(a.w));
    *(ushort4*)(ebf + i + 4) = make_ushort4(f2bf(b.x), f2bf(b.y), f2bf(b.z), f2bf(b.w));
}

// ---------------- znorm + zero loss ----------------
__global__ void k_znorm(const float* __restrict__ z, float* __restrict__ znorm,
                        float* __restrict__ lossAcc) {
    const int n  = blockIdx.x * 256 + threadIdx.x;
    const int b  = n >> 10, hw = n & 1023;
    const float* p = z + (size_t)b * 262144 + hw;
    float s = 0.0f;
#pragma unroll 8
    for (int c = 0; c < CC; ++c) {
        float v = p[(size_t)c * 1024];
        s = fmaf(v, v, s);
    }
    znorm[n] = s;
    if (n == 0) lossAcc[0] = 0.0f;
}

// ---------------- enorm ----------------
__global__ void k_enorm(const float* __restrict__ emb, float* __restrict__ enorm) {
    const int w = threadIdx.x >> 6, lane = threadIdx.x & 63;
    const int k = blockIdx.x * 4 + w;
    float4 v = *(const float4*)(emb + (size_t)k * CC + lane * 4);
    float s = v.x * v.x + v.y * v.y + v.z * v.z + v.w * v.w;
    for (int off = 32; off > 0; off >>= 1) s += __shfl_down(s, off);
    if (lane == 0) enorm[k] = s;
}

// ---------------- Phase 1: bf16 MFMA dot + online max + candidate collection ----------
// 256 blocks x 512 thr (8 waves). Block = 64 n, full 8192 k. Wave w owns k in
// [w*1024,(w+1)*1024), processed in 16 iters of 64k; c in 8 chunks of 32 (dbuf LDS).
// Staging in fragment order: lane's 16B = its MFMA fragment; ds_read_b128 @ lane*16.
// mfma_f32_16x16x32_bf16: A[m=lane&15][c=(lane>>4)*8+j]; B[c][n=lane&15];
// D: col(n)=lane&15, row(k)=(lane>>4)*4+reg.
__global__ __launch_bounds__(512)
void k_phase1(const unsigned short* __restrict__ zb16, const unsigned short* __restrict__ ebf,
              int* __restrict__ candCnt, int* __restrict__ candI) {
    __shared__ short As[2][8][4][512];   // 64 KB  [buf][wave][ktile][lane*8]
    __shared__ short Bs[2][4][512];      // 8 KB   [buf][ntile][lane*8]
    __shared__ float runmax[64];
    __shared__ float wavemax[8][64];
    __shared__ int   cnt[64];
    __shared__ int   lst[64][CAND_CAP];  // 16 KB

    const int tid  = threadIdx.x;
    const int lane = tid & 63;
    const int w    = tid >> 6;
    const int nb   = blockIdx.x << 6;
    const int m16  = lane & 15, q = lane >> 4;

    if (tid < 64) { runmax[tid] = -__builtin_inff(); cnt[tid] = 0; }

    auto stage = [&](int t) {
        const int s = t >> 3, c0 = (t & 7) << 5, buf = t & 1;
        const int kbase = (w << 10) + (s << 6);
#pragma unroll
        for (int kt = 0; kt < 4; ++kt) {
            const unsigned short* g = ebf + (size_t)(kbase + (kt << 4) + m16) * 256 + c0 + q * 8;
            gl_lds16(g, &As[buf][w][kt][lane * 8]);
        }
        if (w < 4) {
            const unsigned short* g = zb16 + (size_t)(nb + (w << 4) + m16) * 256 + c0 + q * 8;
            gl_lds16(g, &Bs[buf][w][lane * 8]);
        }
    };

    stage(0);

    v4f acc[16];
#pragma unroll
    for (int i = 0; i < 16; ++i) acc[i] = (v4f){0.f, 0.f, 0.f, 0.f};

#pragma unroll 1
    for (int t = 0; t < 128; ++t) {
        __syncthreads();
        if (t + 1 < 128) stage(t + 1);
        const int buf = t & 1;
        v8s af[4], bf[4];
#pragma unroll
        for (int kt = 0; kt < 4; ++kt) af[kt] = *(const v8s*)&As[buf][w][kt][lane * 8];
#pragma unroll
        for (int nt = 0; nt < 4; ++nt) bf[nt] = *(const v8s*)&Bs[buf][nt][lane * 8];
#pragma unroll
        for (int kt = 0; kt < 4; ++kt)
#pragma unroll
            for (int nt = 0; nt < 4; ++nt)
                acc[kt * 4 + nt] = __builtin_amdgcn_mfma_f32_16x16x32_bf16(
                    af[kt], bf[nt], acc[kt * 4 + nt], 0, 0, 0);

        if ((t & 7) == 7) {   // end of 64k iter s: reduce max, push candidates
            const int s = t >> 3;
            // per-lane max per ntile, then across the 4 lanes sharing n
#pragma unroll
            for (int nt = 0; nt < 4; ++nt) {
                float m = acc[nt][0];
#pragma unroll
                for (int kt = 0; kt < 4; ++kt)
#pragma unroll
                    for (int r = 0; r < 4; ++r) m = fmaxf(m, acc[kt * 4 + nt][r]);
                m = fmaxf(m, __shfl_xor(m, 16));
                m = fmaxf(m, __shfl_xor(m, 32));
                if (lane < 16) wavemax[w][nt * 16 + lane] = m;
            }
            __syncthreads();
            if (tid < 64) {
                float r = runmax[tid];
#pragma unroll
                for (int ww = 0; ww < 8; ++ww) r = fmaxf(r, wavemax[ww][tid]);
                runmax[tid] = r;
            }
            __syncthreads();
#pragma unroll
            for (int nt = 0; nt < 4; ++nt) {
                const int nl = nt * 16 + m16;
                const float thr = runmax[nl] - MARGIN;
#pragma unroll
                for (int kt = 0; kt < 4; ++kt)
#pragma unroll
                    for (int r = 0; r < 4; ++r) {
                        if (acc[kt * 4 + nt][r] >= thr) {
                            int k = (w << 10) + (s << 6) + (kt << 4) + q * 4 + r;
                            int pos = atomicAdd(&cnt[nl], 1);
                            if (pos < CAND_CAP) lst[nl][pos] = k;
                        }
                    }
            }
#pragma unroll
            for (int i = 0; i < 16; ++i) acc[i] = (v4f){0.f, 0.f, 0.f, 0.f};
        }
    }

    __syncthreads();
    if (tid < 64) {
        const int n = nb + tid;
        const int c = cnt[tid];
        candCnt[n] = c;
        const int m = c < CAND_CAP ? c : CAND_CAP;
        for (int i = 0; i < m; ++i) candI[(size_t)n * CAND_CAP + i] = lst[tid][i];
    }
}

// ---------------- Phase 2: exact fp32 rescore, wave-per-n, lane-parallel dot ----------
// One wave owns one n. Lane l holds z_t[n][4l..4l+3] (coalesced 1 KB row load).
// Per candidate: coalesced emb-row load, 4 fmaf + 6-step butterfly -> uniform dot.
// d chain matches prior kernel: d = (zn + enorm[k]) - (p + p); ties -> smallest k.
__global__ __launch_bounds__(256)
void k_rescore2(const float* __restrict__ zt, const float* __restrict__ emb,
                const float* __restrict__ znorm, const float* __restrict__ enorm,
                const int* __restrict__ candCnt, const int* __restrict__ candI,
                float* __restrict__ idx_out) {
    const int lane = threadIdx.x & 63;
    const int n    = blockIdx.x * 4 + (threadIdx.x >> 6);
    const float zn = znorm[n];
    const int  cnt = candCnt[n];
    const float4 zv = *(const float4*)(zt + (size_t)n * CC + lane * 4);
    float bd = __builtin_inff();
    int   bk = 0x7fffffff;
    if (cnt <= CAND_CAP) {
#pragma unroll 1
        for (int i = 0; i < cnt; ++i) {
            const int k = candI[(size_t)n * CAND_CAP + i];
            const float4 ev = *(const float4*)(emb + (size_t)k * CC + lane * 4);
            float p = zv.x * ev.x;
            p = fmaf(zv.y, ev.y, p);
            p = fmaf(zv.z, ev.z, p);
            p = fmaf(zv.w, ev.w, p);
#pragma unroll
            for (int off = 1; off < 64; off <<= 1) p += __shfl_xor(p, off);
            const float d = (zn + enorm[k]) - (p + p);
            if (d < bd || (d == bd && k < bk)) { bd = d; bk = k; }
        }
    } else {
        // overflow fallback: exact full scan, all lanes active, ascending k keeps min-k
#pragma unroll 1
        for (int k = 0; k < KK; ++k) {
            const float4 ev = *(const float4*)(emb + (size_t)k * CC + lane * 4);
            float p = zv.x * ev.x;
            p = fmaf(zv.y, ev.y, p);
            p = fmaf(zv.z, ev.z, p);
            p = fmaf(zv.w, ev.w, p);
#pragma unroll
            for (int off = 1; off < 64; off <<= 1) p += __shfl_xor(p, off);
            const float d = (zn + enorm[k]) - (p + p);
            if (d < bd) { bd = d; bk = k; }
        }
    }
    if (lane == 0) idx_out[n] = (float)bk;
}

// ---------------- gather z_q (BCHW) + loss partials ----------------
__global__ void k_gather(const float* __restrict__ z, const float* __restrict__ emb,
                         const float* __restrict__ idxf, float* __restrict__ out,
                         float* __restrict__ lossAcc) {
    __shared__ float red[256];
    const int bid = blockIdx.x;
    const int b = bid >> 5, h = bid & 31;
    const int t = threadIdx.x;
    const int w_ = t & 31, cg = t >> 5;
    const int n = b * 1024 + h * 32 + w_;
    const int ki = (int)idxf[n];
    const float* ep = emb + (size_t)ki * CC;
    const size_t base = (size_t)b * 262144 + h * 32 + w_;
    float ls = 0.0f;
#pragma unroll 4
    for (int c = cg; c < CC; c += 8) {
        float e = ep[c];
        size_t a = base + (size_t)c * 1024;
        float zv = z[a];
        out[a] = e;
        float df = e - zv;
        ls = fmaf(df, df, ls);
    }
    red[t] = ls;
    __syncthreads();
    for (int s = 128; s > 0; s >>= 1) {
        if (t < s) red[t] += red[t + s];
        __syncthreads();
    }
    if (t == 0) atomicAdd(lossAcc, red[0]);
}

// ---------------- finalize loss ----------------
__global__ void k_loss(const float* __restrict__ lossAcc, float* __restrict__ outLoss) {
    if (threadIdx.x == 0) {
        float m = lossAcc[0] * (1.0f / 4194304.0f);
        outLoss[0] = m + 0.25f * m;
    }
}

extern "C" void kernel_launch(void* const* d_in, const int* in_sizes, int n_in,
                              void* d_out, int out_size, void* d_ws, size_t ws_size,
                              hipStream_t stream) {
    const float* z   = (const float*)d_in[0];
    const float* emb = (const float*)d_in[1];
    float* outf = (float*)d_out;
    float* wsf  = (float*)d_ws;

    float* lossAcc = wsf;
    float* znorm   = wsf + WS_ZNORM;
    float* enorm   = wsf + WS_ENORM;
    int*   candCnt = (int*)(wsf + WS_CCNT);
    int*   candI   = (int*)(wsf + WS_CIDX);

    // d_out z_q region doubles as scratch: bf16 zb16/ebf until k_phase1 completes,
    // then fp32 z_t until k_gather overwrites it with z_q.
    unsigned short* zb16 = (unsigned short*)outf;                  // 8 MB
    unsigned short* ebf  = (unsigned short*)(outf + 2097152);      // 4 MB
    float* zt = outf;                                              // 16 MB (after phase1)

    k_prep_z<<<dim3(16, 4, 16), 256, 0, stream>>>(z, zb16);
    k_prep_e<<<1024, 256, 0, stream>>>(emb, ebf);
    k_znorm<<<64, 256, 0, stream>>>(z, znorm, lossAcc);
    k_enorm<<<2048, 256, 0, stream>>>(emb, enorm);
    k_phase1<<<256, 512, 0, stream>>>(zb16, ebf, candCnt, candI);
    k_tr_z<<<dim3(16, 4, 16), 256, 0, stream>>>(z, zt);
    k_rescore2<<<4096, 256, 0, stream>>>(zt, emb, znorm, enorm, candCnt, candI, outf + Z_OUT);
    k_gather<<<512, 256, 0, stream>>>(z, emb, outf + Z_OUT, outf, lossAcc);
    k_loss<<<1, 64, 0, stream>>>(lossAcc, outf + Z_OUT + NPTS);
}